// Round 1
// baseline (265.004 us; speedup 1.0000x reference)
//
#include <hip/hip_runtime.h>

#define NN 200000   // nodes
// D = 128 features, 40 classes (padded to 48 in the LDS weight tile)

typedef __attribute__((ext_vector_type(8))) short bf16x8;
typedef __attribute__((ext_vector_type(4))) float f32x4;
typedef __attribute__((ext_vector_type(4))) unsigned int u32x4;

// round-to-nearest-even fp32 -> bf16 bits
static __device__ __forceinline__ short f2bf(float f) {
    unsigned u = __builtin_bit_cast(unsigned, f);
    u += 0x7fffu + ((u >> 16) & 1u);
    return (short)(u >> 16);
}

// XOR-swizzled LDS offset for element (r, k) of a [*,128] bf16 tile.
// 16B chunks within a 256B row are xored with (r&15) -> conflict-free b128 access.
static __device__ __forceinline__ int swz(int r, int k) {
    return (r << 7) + (((k >> 3) ^ (r & 15)) << 3) + (k & 7);
}

// Pre-transpose + bf16-convert weights into workspace:
// wt layout (elements): [0)      Wt0[n][k] = W0[k][n]   128x128
//                       [16384)  Wt1        128x128
//                       [32768)  Wt2        128x128
//                       [49152)  Wt3[n][k]  48x128 (n>=40 zero)
__global__ void prep_weights_k(const float* __restrict__ W0, const float* __restrict__ W1,
                               const float* __restrict__ W2, const float* __restrict__ W3,
                               short* __restrict__ wt) {
    int e = blockIdx.x * 256 + threadIdx.x;   // 216 blocks * 256 = 55296
    if (e < 49152) {
        int l = e >> 14;
        int i = e & 16383;
        int n = i >> 7, k = i & 127;
        const float* W = (l == 0) ? W0 : ((l == 1) ? W1 : W2);
        wt[e] = f2bf(W[(k << 7) + n]);
    } else if (e < 55296) {
        int i = e - 49152;
        int n = i >> 7, k = i & 127;
        wt[e] = (n < 40) ? f2bf(W3[k * 40 + n]) : (short)0;
    }
}

__global__ __launch_bounds__(256, 2)
void mlp_fused_k(const float* __restrict__ x, const short* __restrict__ wt,
                 const float* __restrict__ b0, const float* __restrict__ b1,
                 const float* __restrict__ b2, const float* __restrict__ b3,
                 float* __restrict__ out) {
    // 64 KB total static LDS -> 2 blocks/CU
    __shared__ __align__(16) short sA[128 * 128];  // activations, bf16, swizzled
    __shared__ __align__(16) short sW[128 * 128];  // current layer W^T, bf16, swizzled

    const int tid  = (int)threadIdx.x;
    const int lane = tid & 63;
    const int wv   = tid >> 6;       // wave 0..3
    const int m    = lane & 15;      // row (A) / col (B,C) within 16-tile
    const int quad = lane >> 4;      // 0..3
    const int rb   = (int)blockIdx.x * 128;  // block row base
    const int rwb  = wv * 32;                // wave row base within block

    // cooperative stage of one weight tile from ws into sW (16B chunks, swizzled)
    auto stageW = [&](int chunk_base, int nchunks) {
        const u32x4* src = (const u32x4*)wt + chunk_base;
        #pragma unroll
        for (int i = 0; i < 8; ++i) {
            int q = tid + (i << 8);
            if (q < nchunks) {
                int r = q >> 4, c = q & 15;
                *(u32x4*)&sW[(r << 7) + ((c ^ (r & 15)) << 3)] = src[q];
            }
        }
    };

    f32x4 acc[2][8];
    auto zacc = [&]() {
        #pragma unroll
        for (int rt = 0; rt < 2; ++rt)
            #pragma unroll
            for (int ct = 0; ct < 8; ++ct)
                #pragma unroll
                for (int r = 0; r < 4; ++r) acc[rt][ct][r] = 0.f;
    };

    // layers 1,2: A fragments from sA
    auto computeA = [&]() {
        zacc();
        #pragma unroll
        for (int ks = 0; ks < 4; ++ks) {
            int kk = (ks << 5) + (quad << 3);
            bf16x8 a0 = *(const bf16x8*)&sA[swz(rwb + m, kk)];
            bf16x8 a1 = *(const bf16x8*)&sA[swz(rwb + 16 + m, kk)];
            #pragma unroll
            for (int ct = 0; ct < 8; ++ct) {
                bf16x8 b = *(const bf16x8*)&sW[swz((ct << 4) + m, kk)];
                acc[0][ct] = __builtin_amdgcn_mfma_f32_16x16x32_bf16(a0, b, acc[0][ct], 0, 0, 0);
                acc[1][ct] = __builtin_amdgcn_mfma_f32_16x16x32_bf16(a1, b, acc[1][ct], 0, 0, 0);
            }
        }
    };

    // bias + SiLU + bf16 -> sA (each wave writes only its own 32 rows)
    auto epilogue = [&](const float* __restrict__ bias) {
        float bv[8];
        #pragma unroll
        for (int ct = 0; ct < 8; ++ct) bv[ct] = bias[(ct << 4) + m];
        #pragma unroll
        for (int rt = 0; rt < 2; ++rt)
            #pragma unroll
            for (int ct = 0; ct < 8; ++ct)
                #pragma unroll
                for (int r = 0; r < 4; ++r) {
                    float v = acc[rt][ct][r] + bv[ct];
                    float h = v * __builtin_amdgcn_rcpf(1.f + __expf(-v));
                    int rl = rwb + (rt << 4) + (quad << 2) + r;   // C/D: row = quad*4+reg
                    sA[swz(rl, (ct << 4) + m)] = f2bf(h);         // col = lane&15
                }
    };

    // ---------------- layer 0: A direct from global x ----------------
    stageW(0, 2048);
    __syncthreads();
    zacc();
    {
        int g0 = rb + rwb + m, g1 = g0 + 16;
        int row0 = (g0 < NN) ? g0 : (NN - 1);
        int row1 = (g1 < NN) ? g1 : (NN - 1);
        const float* p0 = x + ((long)row0 << 7) + (quad << 3);
        const float* p1 = x + ((long)row1 << 7) + (quad << 3);
        #pragma unroll
        for (int ks = 0; ks < 4; ++ks) {
            f32x4 v0a = *(const f32x4*)(p0 + (ks << 5));
            f32x4 v0b = *(const f32x4*)(p0 + (ks << 5) + 4);
            f32x4 v1a = *(const f32x4*)(p1 + (ks << 5));
            f32x4 v1b = *(const f32x4*)(p1 + (ks << 5) + 4);
            bf16x8 a0, a1;
            #pragma unroll
            for (int j = 0; j < 4; ++j) {
                a0[j] = f2bf(v0a[j]); a0[j + 4] = f2bf(v0b[j]);
                a1[j] = f2bf(v1a[j]); a1[j + 4] = f2bf(v1b[j]);
            }
            int kk = (ks << 5) + (quad << 3);
            #pragma unroll
            for (int ct = 0; ct < 8; ++ct) {
                bf16x8 b = *(const bf16x8*)&sW[swz((ct << 4) + m, kk)];
                acc[0][ct] = __builtin_amdgcn_mfma_f32_16x16x32_bf16(a0, b, acc[0][ct], 0, 0, 0);
                acc[1][ct] = __builtin_amdgcn_mfma_f32_16x16x32_bf16(a1, b, acc[1][ct], 0, 0, 0);
            }
        }
    }
    __syncthreads();
    epilogue(b0);
    stageW(2048, 2048);
    __syncthreads();

    // ---------------- layers 1,2 ----------------
    computeA();
    __syncthreads();
    epilogue(b1);
    stageW(4096, 2048);
    __syncthreads();

    computeA();
    __syncthreads();
    epilogue(b2);
    stageW(6144, 768);           // W3^T: 48 rows x 128
    __syncthreads();

    // ---------------- layer 3 + log_softmax ----------------
    f32x4 c3[2][3];
    #pragma unroll
    for (int rt = 0; rt < 2; ++rt)
        #pragma unroll
        for (int ct = 0; ct < 3; ++ct)
            #pragma unroll
            for (int r = 0; r < 4; ++r) c3[rt][ct][r] = 0.f;
    #pragma unroll
    for (int ks = 0; ks < 4; ++ks) {
        int kk = (ks << 5) + (quad << 3);
        bf16x8 a0 = *(const bf16x8*)&sA[swz(rwb + m, kk)];
        bf16x8 a1 = *(const bf16x8*)&sA[swz(rwb + 16 + m, kk)];
        #pragma unroll
        for (int ct = 0; ct < 3; ++ct) {
            bf16x8 b = *(const bf16x8*)&sW[swz((ct << 4) + m, kk)];
            c3[0][ct] = __builtin_amdgcn_mfma_f32_16x16x32_bf16(a0, b, c3[0][ct], 0, 0, 0);
            c3[1][ct] = __builtin_amdgcn_mfma_f32_16x16x32_bf16(a1, b, c3[1][ct], 0, 0, 0);
        }
    }
    const bool val2 = (m < 8);                    // cols 32..39 valid
    float bv0 = b3[m];
    float bv1 = b3[16 + m];
    float bv2 = val2 ? b3[32 + m] : 0.f;
    #pragma unroll
    for (int rt = 0; rt < 2; ++rt) {
        #pragma unroll
        for (int r = 0; r < 4; ++r) {
            float v0 = c3[rt][0][r] + bv0;
            float v1 = c3[rt][1][r] + bv1;
            float v2 = c3[rt][2][r] + bv2;
            // row lives on the 16 lanes of this quad; reduce over cols 0..39
            float mx = fmaxf(v0, v1);
            mx = val2 ? fmaxf(mx, v2) : mx;
            #pragma unroll
            for (int s = 1; s < 16; s <<= 1)
                mx = fmaxf(mx, __shfl_xor(mx, s, 64));
            float sm = __expf(v0 - mx) + __expf(v1 - mx) + (val2 ? __expf(v2 - mx) : 0.f);
            #pragma unroll
            for (int s = 1; s < 16; s <<= 1)
                sm += __shfl_xor(sm, s, 64);
            float L = mx + __logf(sm);
            int grow = rb + rwb + (rt << 4) + (quad << 2) + r;
            if (grow < NN) {
                float* orow = out + (long)grow * 40;
                orow[m]      = v0 - L;
                orow[16 + m] = v1 - L;
                if (val2) orow[32 + m] = v2 - L;
            }
        }
    }
}

extern "C" void kernel_launch(void* const* d_in, const int* in_sizes, int n_in,
                              void* d_out, int out_size, void* d_ws, size_t ws_size,
                              hipStream_t stream) {
    const float* x   = (const float*)d_in[0];
    // d_in[1] = edge_index (unused: ChebConv K=1 ignores the Laplacian)
    const float* W0  = (const float*)d_in[2];
    const float* bb0 = (const float*)d_in[3];
    const float* W1  = (const float*)d_in[4];
    const float* bb1 = (const float*)d_in[5];
    const float* W2  = (const float*)d_in[6];
    const float* bb2 = (const float*)d_in[7];
    const float* W3  = (const float*)d_in[8];
    const float* bb3 = (const float*)d_in[9];
    short* wt  = (short*)d_ws;         // 110592 B of bf16 transposed weights
    float* out = (float*)d_out;

    hipLaunchKernelGGL(prep_weights_k, dim3(216), dim3(256), 0, stream, W0, W1, W2, W3, wt);
    hipLaunchKernelGGL(mlp_fused_k, dim3((NN + 127) / 128), dim3(256), 0, stream,
                       x, wt, bb0, bb1, bb2, bb3, out);
}